// Round 11
// baseline (32.628 us; speedup 1.0000x reference)
//
#include <hip/hip_runtime.h>

// Chamfer via MFMA, round 11: occupancy push (latency-bound diagnosis).
// Round-10 post-mortem: no pipe saturated; 4 waves/SIMD capped by 33KB LDS
// and 4-acc-tile VGPR footprint. This round: 2 query-tiles/wave (acc 32 VGPR,
// est total ~76 <= 85), JCHUNK=512 (17KB LDS), __launch_bounds__(256,6)
// -> 6 blocks/CU = 6 waves/SIMD (75% occupancy). setprio(1) around MFMA pair
// (independent-wave regime = attn-like, m191). Loss pass fused to 1 dispatch.
// Swapped operands (validated round 10, absmax 0): mfma(target, query) ->
// lane=query, regs=16 targets; row-max = in-register max3 tree, no shuffles.
// NJ=16 chunks merged via atomicMax on order-encoded u32 (deterministic).
// bf16 hi/lo rep (validated rounds 3-10, absmax 0):
//   A_rep(q) = [qh(3), ql(3), qh(3), hq_h, hq_l,  1,  1, 0,0,0]
//   B_rep(t) = [th(3), th(3), tl(3),  -1,  -1, -ht_h, -ht_l, 0,0,0]

#define NPTS    8192
#define BATCH   4
#define NJ      16
#define JCHUNK  512                // targets per block chunk: 16 tiles, 16 KB
#define JTILES  (JCHUNK / 32)      // 16
#define NSLOTS  (2 * BATCH * NPTS) // 65536

typedef __attribute__((ext_vector_type(8))) short short8v;
typedef __attribute__((ext_vector_type(16))) float f32x16;

__device__ __forceinline__ unsigned enc_f32(float f) {
  unsigned u = __float_as_uint(f);
  return (u & 0x80000000u) ? ~u : (u | 0x80000000u);
}
__device__ __forceinline__ float dec_f32(unsigned u) {
  u = (u & 0x80000000u) ? (u ^ 0x80000000u) : ~u;
  return __uint_as_float(u);
}
__device__ __forceinline__ unsigned short f2bf(float x) {   // RNE bf16
  unsigned u = __float_as_uint(x);
  unsigned r = u + 0x7FFFu + ((u >> 16) & 1u);
  return (unsigned short)(r >> 16);
}
__device__ __forceinline__ float bf2f(unsigned short b) {
  return __uint_as_float((unsigned)b << 16);
}

// Tiled rep: element offset for point j (batch b), k-half h:
//   b*131072 + (j>>5)*512 + h*256 + (j&31)*8   [shorts]
__global__ __launch_bounds__(256) void prep(
    const float* __restrict__ c1, const float* __restrict__ c2,
    unsigned short* __restrict__ a1, unsigned short* __restrict__ a2,
    unsigned short* __restrict__ b1, unsigned short* __restrict__ b2,
    unsigned* __restrict__ rowbuf) {
  int pid = blockIdx.x * 256 + threadIdx.x;
  if (pid >= BATCH * NPTS) return;
  rowbuf[pid] = 0u;                    // below enc of any real float
  rowbuf[pid + BATCH * NPTS] = 0u;
  const unsigned short one = 0x3F80u, negone = 0xBF80u;
  int b = pid >> 13, j = pid & (NPTS - 1);
  size_t off0 = (size_t)b * 131072 + (size_t)(j >> 5) * 512 + (size_t)(j & 31) * 8;
  const float* cs[2] = {c1, c2};
  unsigned short* as[2] = {a1, a2};
  unsigned short* bs[2] = {b1, b2};
  #pragma unroll
  for (int c = 0; c < 2; ++c) {
    float x = cs[c][pid * 3 + 0], y = cs[c][pid * 3 + 1], z = cs[c][pid * 3 + 2];
    unsigned short xh = f2bf(x), yh = f2bf(y), zh = f2bf(z);
    unsigned short xl = f2bf(x - bf2f(xh)), yl = f2bf(y - bf2f(yh)),
                   zl = f2bf(z - bf2f(zh));
    float hn = 0.5f * (x * x + y * y + z * z);
    unsigned short hh = f2bf(hn), hl = f2bf(hn - bf2f(hh));
    unsigned short va[16] = {xh, yh, zh, xl, yl, zl, xh, yh, zh,
                             hh, hl, one, one, 0, 0, 0};
    unsigned short nh = hh ^ 0x8000u, nl = hl ^ 0x8000u;
    unsigned short vb[16] = {xh, yh, zh, xh, yh, zh, xl, yl, zl,
                             negone, negone, nh, nl, 0, 0, 0};
    *(uint4*)(as[c] + off0)       = *(const uint4*)&va[0];
    *(uint4*)(as[c] + off0 + 256) = *(const uint4*)&va[8];
    *(uint4*)(bs[c] + off0)       = *(const uint4*)&vb[0];
    *(uint4*)(bs[c] + off0 + 256) = *(const uint4*)&vb[8];
  }
}

// max3 tree over the 16 acc regs (targets) + running max: 8 VALU ops.
__device__ __forceinline__ float tree17(const f32x16& c, float m) {
  float t0 = fmaxf(fmaxf(c[0],  c[1]),  c[2]);    // v_max3_f32
  float t1 = fmaxf(fmaxf(c[3],  c[4]),  c[5]);
  float t2 = fmaxf(fmaxf(c[6],  c[7]),  c[8]);
  float t3 = fmaxf(fmaxf(c[9],  c[10]), c[11]);
  float t4 = fmaxf(fmaxf(c[12], c[13]), c[14]);
  float u0 = fmaxf(fmaxf(t0, t1), t2);
  float u1 = fmaxf(fmaxf(t3, t4), c[15]);
  return fmaxf(fmaxf(u0, u1), m);
}

// grid = 2(dir) x 4(b) x 32(ig: 256 queries) x 16(jc) = 4096 blocks x 4 waves.
// Wave owns 2 query-tiles (64 queries); block stages 512 targets (16 KB
// + 1-tile prefetch pad) and loops 16 target tiles.
__global__ __launch_bounds__(256, 6) void chamfer_mfma(
    const unsigned short* __restrict__ a1, const unsigned short* __restrict__ a2,
    const unsigned short* __restrict__ b1, const unsigned short* __restrict__ b2,
    unsigned* __restrict__ rowbuf) {
  __shared__ __align__(16) unsigned short sB[(JCHUNK + 32) * 16];  // 17 KB

  int bid = blockIdx.x;
  int jc  = bid & (NJ - 1);
  int ig  = (bid >> 4) & 31;
  int b   = (bid >> 9) & 3;
  int dir = bid >> 11;

  const unsigned short* A = dir ? a2 : a1;   // queries (tiled rep)
  const unsigned short* B = dir ? b1 : b2;   // targets (tiled rep)

  int wave = threadIdx.x >> 6;
  int lane = threadIdx.x & 63;
  int p = lane & 31, h = lane >> 5;

  // ---- stage 16 KB target chunk linearly: 4 waves x 4 x (64 x 16 B) ----
  {
    const char* gb = (const char*)B + (size_t)b * 262144 + (size_t)jc * 16384
                     + wave * 4096 + lane * 16;
    char* lb = (char*)sB + wave * 4096;
    #pragma unroll
    for (int k = 0; k < 4; ++k) {
      __builtin_amdgcn_global_load_lds(
          (const __attribute__((address_space(1))) unsigned int*)(gb + k * 1024),
          (__attribute__((address_space(3))) unsigned int*)(lb + k * 1024),
          16, 0, 0);
    }
  }

  // query fragments: 2 consecutive tiles, contiguous 16 B/lane
  int q0 = ig * 256 + wave * 64;
  const unsigned short* Ap =
      A + (size_t)b * 131072 + (size_t)(q0 >> 5) * 512 + h * 256 + p * 8;
  short8v aq0 = *(const short8v*)(const void*)(Ap);
  short8v aq1 = *(const short8v*)(const void*)(Ap + 512);

  f32x16 zero;
  #pragma unroll
  for (int i = 0; i < 16; ++i) zero[i] = 0.0f;
  float m0 = -3.4e38f, m1 = -3.4e38f;

  __syncthreads();   // drains global_load_lds + barrier (only barrier)

  const char* sp = (const char*)sB + lane * 16;   // contiguous: conflict-free
  short8v bt = *(const short8v*)(const void*)(sp);

  #pragma unroll 1
  for (int jt = 0; jt < JTILES; ++jt) {
    short8v btn = *(const short8v*)(const void*)(sp + (size_t)(jt + 1) * 1024);
    __builtin_amdgcn_s_setprio(1);
    // swapped operands: rows(regs)=targets, cols(lanes)=queries
    f32x16 c0 = __builtin_amdgcn_mfma_f32_32x32x16_bf16(bt, aq0, zero, 0, 0, 0);
    f32x16 c1 = __builtin_amdgcn_mfma_f32_32x32x16_bf16(bt, aq1, zero, 0, 0, 0);
    __builtin_amdgcn_s_setprio(0);
    m0 = tree17(c0, m0);   // in-lane: 16 targets for THIS lane's query
    m1 = tree17(c1, m1);
    bt = btn;
  }

  // lane L and L^32 hold the two target-halves of the same query
  m0 = fmaxf(m0, __shfl_xor(m0, 32, 64));
  m1 = fmaxf(m1, __shfl_xor(m1, 32, 64));

  unsigned* rb = rowbuf + ((size_t)dir * BATCH + b) * NPTS + q0;
  if (lane < 32) {                       // NJ=16 contenders, deterministic
    atomicMax(rb + p,      enc_f32(m0));
    atomicMax(rb + 32 + p, enc_f32(m1));
  }
}

__global__ __launch_bounds__(1024) void loss_final(
    const unsigned* __restrict__ rowbuf, float* __restrict__ out) {
  int tid = threadIdx.x;
  const uint4* rb4 = (const uint4*)rowbuf;   // 16384 uint4
  float s = 0.0f;
  #pragma unroll
  for (int k = 0; k < NSLOTS / 4096; ++k) {  // 16 iters
    uint4 u = rb4[k * 1024 + tid];
    s = fmaf(-2.0f, dec_f32(u.x), s);
    s = fmaf(-2.0f, dec_f32(u.y), s);
    s = fmaf(-2.0f, dec_f32(u.z), s);
    s = fmaf(-2.0f, dec_f32(u.w), s);
  }
  #pragma unroll
  for (int off = 32; off > 0; off >>= 1) s += __shfl_down(s, off, 64);
  __shared__ float wsum[16];
  if ((tid & 63) == 0) wsum[tid >> 6] = s;
  __syncthreads();
  if (tid == 0) {
    float t = 0.0f;
    #pragma unroll
    for (int w2 = 0; w2 < 16; ++w2) t += wsum[w2];
    out[0] = t;
  }
}

extern "C" void kernel_launch(void* const* d_in, const int* in_sizes, int n_in,
                              void* d_out, int out_size, void* d_ws, size_t ws_size,
                              hipStream_t stream) {
  const float* c1 = (const float*)d_in[0];
  const float* c2 = (const float*)d_in[1];
  float* out = (float*)d_out;

  char* ws = (char*)d_ws;
  unsigned* rowbuf = (unsigned*)ws;                          // 65536 u32 = 256 KB
  unsigned short* a1 = (unsigned short*)(ws + (size_t)NSLOTS * 4);
  unsigned short* a2 = a1 + (size_t)BATCH * NPTS * 16;       // 1 MB each
  unsigned short* b1 = a2 + (size_t)BATCH * NPTS * 16;
  unsigned short* b2 = b1 + (size_t)BATCH * NPTS * 16;

  prep<<<(BATCH * NPTS) / 256, 256, 0, stream>>>(c1, c2, a1, a2, b1, b2, rowbuf);
  chamfer_mfma<<<2 * BATCH * 32 * NJ, 256, 0, stream>>>(a1, a2, b1, b2, rowbuf);
  loss_final<<<1, 1024, 0, stream>>>(rowbuf, out);
}